// Round 6
// baseline (110.835 us; speedup 1.0000x reference)
//
#include <hip/hip_runtime.h>
#include <hip/hip_bf16.h>
#include <cmath>

typedef __attribute__((ext_vector_type(8))) short short8;
typedef __attribute__((ext_vector_type(4))) float f32x4;

#define EPS_F 1e-7f
#define NEG_DIAG_F -10.0f
#define NPART 192           // per-row max slots: 128 direct (bx) + 64 transposed (by)

// ---------------------------------------------------------------------------
// Kernel 1: row L2-normalize feat_k / feat_g (f32), cast to bf16; zero P.
// ---------------------------------------------------------------------------
__global__ void norm_cast_kernel(const float* __restrict__ fk, const float* __restrict__ fg,
                                 __hip_bfloat16* __restrict__ fkb, __hip_bfloat16* __restrict__ fgb,
                                 float* __restrict__ P, int N, int D) {
    int n = blockIdx.x;
    int t = threadIdx.x;
    float xk = fk[(size_t)n * D + t];
    float xg = fg[(size_t)n * D + t];
    float sk = xk * xk, sg = xg * xg;
#pragma unroll
    for (int off = 32; off > 0; off >>= 1) {
        sk += __shfl_xor(sk, off, 64);
        sg += __shfl_xor(sg, off, 64);
    }
    __shared__ float lsk[4], lsg[4];
    int w = t >> 6, l = t & 63;
    if (l == 0) { lsk[w] = sk; lsg[w] = sg; }
    __syncthreads();
    sk = lsk[0] + lsk[1] + lsk[2] + lsk[3];
    sg = lsg[0] + lsg[1] + lsg[2] + lsg[3];
    float rkv = 1.0f / (sqrtf(sk) + EPS_F);
    float rgv = 1.0f / (sqrtf(sg) + EPS_F);
    fkb[(size_t)n * D + t] = __float2bfloat16(xk * rkv);
    fgb[(size_t)n * D + t] = __float2bfloat16(xg * rgv);
    if (t < NPART) P[(size_t)n * NPART + t] = 0.0f;
}

// ---------------------------------------------------------------------------
// Kernel 2: one wave (64 threads) per 64x32 upper-triangle tile.  Fragments
// read DIRECTLY from global (L2-resident, no LDS staging, no barriers).
// Writes the tile + transposed tile (LDS bounce for full-line coalescing)
// and per-tile row/col maxes to unique P slots (no atomics).
// ---------------------------------------------------------------------------
__global__ __launch_bounds__(64) void gram_wave_kernel(
    const __hip_bfloat16* __restrict__ fkb, const __hip_bfloat16* __restrict__ fgb,
    float* __restrict__ out, float* __restrict__ P, int N, int D) {

    int bx = blockIdx.x, by = blockIdx.y;
    if (bx < 2 * by) return;                 // lower triangle: skip
    int r0 = by * 64, c0 = bx * 32;

    int l = threadIdx.x;
    int lr = l & 15, lg = l >> 4;

    __shared__ __align__(16) float bnc[64 * 36];   // 9216 B; reused as [32][68]

    f32x4 acck[4][2], accg[4][2];
    f32x4 zero = {0.f, 0.f, 0.f, 0.f};
#pragma unroll
    for (int m = 0; m < 4; ++m)
#pragma unroll
        for (int n = 0; n < 2; ++n) { acck[m][n] = zero; accg[m][n] = zero; }

    // per-lane fragment base pointers (row-major, k contiguous)
    const __hip_bfloat16* bAk = fkb + (size_t)(r0 + lr) * D + lg * 8;
    const __hip_bfloat16* bAg = fgb + (size_t)(r0 + lr) * D + lg * 8;
    const __hip_bfloat16* bBk = fkb + (size_t)(c0 + lr) * D + lg * 8;
    const __hip_bfloat16* bBg = fgb + (size_t)(c0 + lr) * D + lg * 8;
    size_t rstep = (size_t)16 * D;

#pragma unroll
    for (int kk = 0; kk < 8; ++kk) {
        short8 ak[4], ag[4], bk[2], bg[2];
#pragma unroll
        for (int m = 0; m < 4; ++m) {
            ak[m] = *(const short8*)(bAk + (size_t)m * rstep + kk * 32);
            ag[m] = *(const short8*)(bAg + (size_t)m * rstep + kk * 32);
        }
#pragma unroll
        for (int n = 0; n < 2; ++n) {
            bk[n] = *(const short8*)(bBk + (size_t)n * rstep + kk * 32);
            bg[n] = *(const short8*)(bBg + (size_t)n * rstep + kk * 32);
        }
        __builtin_amdgcn_s_setprio(1);
#pragma unroll
        for (int m = 0; m < 4; ++m)
#pragma unroll
            for (int n = 0; n < 2; ++n) {
                acck[m][n] = __builtin_amdgcn_mfma_f32_16x16x32_bf16(ak[m], bk[n], acck[m][n], 0, 0, 0);
                accg[m][n] = __builtin_amdgcn_mfma_f32_16x16x32_bf16(ag[m], bg[n], accg[m][n], 0, 0, 0);
            }
        __builtin_amdgcn_s_setprio(0);
    }

    // --- ratio + diag (in place) -------------------------------------------
#pragma unroll
    for (int m = 0; m < 4; ++m)
#pragma unroll
        for (int j = 0; j < 4; ++j) {
            int lrow = m * 16 + lg * 4 + j;
#pragma unroll
            for (int n = 0; n < 2; ++n) {
                float dk = acck[m][n][j];
                float dg = accg[m][n][j];
                float s = (dk + 1.0f + EPS_F) * __builtin_amdgcn_rcpf(dg + 1.0f + EPS_F);
                if (r0 + lrow == c0 + n * 16 + lr) s = NEG_DIAG_F;
                acck[m][n][j] = s;
            }
        }

    // --- row maxes -> P[row][bx] (unique writer per slot) -------------------
#pragma unroll
    for (int m = 0; m < 4; ++m)
#pragma unroll
        for (int j = 0; j < 4; ++j) {
            float pm = fmaxf(acck[m][0][j], acck[m][1][j]);
#pragma unroll
            for (int off = 1; off < 16; off <<= 1)
                pm = fmaxf(pm, __shfl_xor(pm, off, 64));
            if (lr == 0)
                P[(size_t)(r0 + m * 16 + lg * 4 + j) * NPART + bx] = pm;
        }

    bool doT = (bx > 2 * by + 1);   // diagonal-straddling tiles skip transpose
    if (doT) {
        // col maxes -> P[col][128+by]
#pragma unroll
        for (int n = 0; n < 2; ++n) {
            float cm = acck[0][n][0];
#pragma unroll
            for (int m = 0; m < 4; ++m)
#pragma unroll
                for (int j = 0; j < 4; ++j) cm = fmaxf(cm, acck[m][n][j]);
            cm = fmaxf(cm, __shfl_xor(cm, 16, 64));
            cm = fmaxf(cm, __shfl_xor(cm, 32, 64));
            if (lg == 0)
                P[(size_t)(c0 + n * 16 + lr) * NPART + 128 + by] = cm;
        }
    }

    // --- direct tile: bounce -> [64][36], store 128B full rows --------------
#pragma unroll
    for (int m = 0; m < 4; ++m)
#pragma unroll
        for (int n = 0; n < 2; ++n)
#pragma unroll
            for (int j = 0; j < 4; ++j)
                bnc[(m * 16 + lg * 4 + j) * 36 + n * 16 + lr] = acck[m][n][j];
    __syncthreads();
#pragma unroll
    for (int i = 0; i < 8; ++i) {
        int rr = i * 8 + (l >> 3);
        f32x4 v = *(const f32x4*)&bnc[rr * 36 + (l & 7) * 4];
        *(f32x4*)(out + (size_t)(r0 + rr) * N + c0 + (l & 7) * 4) = v;
    }

    if (doT) {
        __syncthreads();
        // transposed tile: bounce -> [32][68], store 256B row segments
#pragma unroll
        for (int m = 0; m < 4; ++m)
#pragma unroll
            for (int n = 0; n < 2; ++n)
#pragma unroll
                for (int j = 0; j < 4; ++j)
                    bnc[(n * 16 + lr) * 68 + m * 16 + lg * 4 + j] = acck[m][n][j];
        __syncthreads();
#pragma unroll
        for (int i = 0; i < 8; ++i) {
            int tr = i * 4 + (l >> 4);
            f32x4 v = *(const f32x4*)&bnc[tr * 68 + (l & 15) * 4];
            *(f32x4*)(out + (size_t)(c0 + tr) * N + r0 + (l & 15) * 4) = v;
        }
    }
}

// ---------------------------------------------------------------------------
// Kernel 3: one block per row: m = max_j P[row][j]; out = exp(out - m).
// ---------------------------------------------------------------------------
__global__ void finalize_kernel(float* __restrict__ out, const float* __restrict__ P, int N) {
    int row = blockIdx.x;
    int t = threadIdx.x;            // 256
    int j = t & 63;
    float m = P[(size_t)row * NPART + j];
    m = fmaxf(m, P[(size_t)row * NPART + 64 + j]);
    m = fmaxf(m, P[(size_t)row * NPART + 128 + j]);
#pragma unroll
    for (int off = 1; off < 64; off <<= 1)
        m = fmaxf(m, __shfl_xor(m, off, 64));
    float4* o4 = (float4*)(out + (size_t)row * N);
    int n4 = N >> 2;
    for (int i = t; i < n4; i += 256) {
        float4 v = o4[i];
        v.x = __expf(v.x - m);
        v.y = __expf(v.y - m);
        v.z = __expf(v.z - m);
        v.w = __expf(v.w - m);
        o4[i] = v;
    }
}

// ---------------------------------------------------------------------------
extern "C" void kernel_launch(void* const* d_in, const int* in_sizes, int n_in,
                              void* d_out, int out_size, void* d_ws, size_t ws_size,
                              hipStream_t stream) {
    const float* fk = (const float*)d_in[1];
    const float* fg = (const float*)d_in[2];
    float* out = (float*)d_out;

    int N = (int)llround(sqrt((double)out_size));   // 4096
    int D = in_sizes[1] / N;                        // 256

    char* ws = (char*)d_ws;
    float* P = (float*)ws;                                          // N*192*4 = 3 MB
    __hip_bfloat16* fkb = (__hip_bfloat16*)(ws + (size_t)N * NPART * 4);
    __hip_bfloat16* fgb = (__hip_bfloat16*)(ws + (size_t)N * NPART * 4 + (size_t)N * D * 2);

    norm_cast_kernel<<<N, D, 0, stream>>>(fk, fg, fkb, fgb, P, N, D);

    gram_wave_kernel<<<dim3(N / 32, N / 64), 64, 0, stream>>>(fkb, fgb, out, P, N, D);

    finalize_kernel<<<N, 256, 0, stream>>>(out, P, N);
}

// Round 7
// 68.635 us; speedup vs baseline: 1.6148x; 1.6148x over previous
//
#include <hip/hip_runtime.h>
#include <hip/hip_bf16.h>
#include <cmath>

typedef __attribute__((ext_vector_type(8))) short short8;
typedef __attribute__((ext_vector_type(4))) float f32x4;

#define EPS_F 1e-7f
#define NEG_DIAG_F -10.0f
#define NPART 128           // per-row max slots: 64 direct (bx) + 64 transposed (by)

__device__ __forceinline__ void gload_lds16(const void* gptr, void* ldsptr) {
    __builtin_amdgcn_global_load_lds(
        (const __attribute__((address_space(1))) unsigned int*)gptr,
        (__attribute__((address_space(3))) unsigned int*)ldsptr,
        16, 0, 0);
}

// ---------------------------------------------------------------------------
// Kernel 1: row L2-normalize feat_k / feat_g (f32), cast to bf16; zero P.
// ---------------------------------------------------------------------------
__global__ void norm_cast_kernel(const float* __restrict__ fk, const float* __restrict__ fg,
                                 __hip_bfloat16* __restrict__ fkb, __hip_bfloat16* __restrict__ fgb,
                                 float* __restrict__ P, int N, int D) {
    int n = blockIdx.x;
    int t = threadIdx.x;
    float xk = fk[(size_t)n * D + t];
    float xg = fg[(size_t)n * D + t];
    float sk = xk * xk, sg = xg * xg;
#pragma unroll
    for (int off = 32; off > 0; off >>= 1) {
        sk += __shfl_xor(sk, off, 64);
        sg += __shfl_xor(sg, off, 64);
    }
    __shared__ float lsk[4], lsg[4];
    int w = t >> 6, l = t & 63;
    if (l == 0) { lsk[w] = sk; lsg[w] = sg; }
    __syncthreads();
    sk = lsk[0] + lsk[1] + lsk[2] + lsk[3];
    sg = lsg[0] + lsg[1] + lsg[2] + lsg[3];
    float rkv = 1.0f / (sqrtf(sk) + EPS_F);
    float rgv = 1.0f / (sqrtf(sg) + EPS_F);
    fkb[(size_t)n * D + t] = __float2bfloat16(xk * rkv);
    fgb[(size_t)n * D + t] = __float2bfloat16(xg * rgv);
    if (t < NPART) P[(size_t)n * NPART + t] = 0.0f;
}

// ---------------------------------------------------------------------------
// Kernel 2: 64x64-tile upper-triangle dual Gram, 4 waves (2x2), BK=32.
// 17.9 KB LDS -> 5+ blocks/CU resident; 2080 working blocks interleave
// stage/compute/store phases across blocks.  Writes tile + transposed tile
// (bounce-coalesced 256B rows) and per-tile row/col maxes to unique P slots.
// ---------------------------------------------------------------------------
__global__ __launch_bounds__(256, 5) void gram64_kernel(
    const __hip_bfloat16* __restrict__ fkb, const __hip_bfloat16* __restrict__ fgb,
    float* __restrict__ out, float* __restrict__ P, int N, int D) {

    __shared__ __align__(16) char smem[17408 + 512];   // staging(16K) ∪ bounce(17K), lmax
    float* bnc = (float*)smem;                          // [64][68] f32
    int* lmax = (int*)(smem + 17408);                   // [0..63] row, [64..127] col

    int bx = blockIdx.x, by = blockIdx.y;
    if (bx < by) return;                                // lower triangle: skip
    int r0 = by * 64, c0 = bx * 64;

    int t = threadIdx.x;
    int w = t >> 6, l = t & 63;
    int wr = w >> 1, wc = w & 1;    // 2x2 wave grid; wave tile = 32 rows x 32 cols
    int lr = l & 15, lg = l >> 4;

    if (t < NPART) lmax[t] = 0;     // positive floats compare as ints

    // LDS read offsets (constant across K-steps): granule ^= (row>>1)&3
    int aoff[2], boff[2];
#pragma unroll
    for (int m = 0; m < 2; ++m) {
        int row = wr * 32 + m * 16 + lr;
        aoff[m] = row * 64 + ((lg ^ ((row >> 1) & 3)) << 4);
    }
#pragma unroll
    for (int n = 0; n < 2; ++n) {
        int row = wc * 32 + n * 16 + lr;
        boff[n] = row * 64 + ((lg ^ ((row >> 1) & 3)) << 4);
    }

    // staging addresses: thread t -> row t>>2, granule t&3, inverse-swizzled src
    int srow = t >> 2;
    int scsw = ((t & 3) ^ ((srow >> 1) & 3)) << 4;
    const size_t rowbytes = (size_t)D * 2;
    size_t gA = (size_t)(r0 + srow) * rowbytes + scsw;
    size_t gB = (size_t)(c0 + srow) * rowbytes + scsw;
    int sdst = (t >> 6) << 10;      // wave-uniform dest base (HW adds lane*16)

    f32x4 acck[2][2], accg[2][2];
    f32x4 zero = {0.f, 0.f, 0.f, 0.f};
#pragma unroll
    for (int m = 0; m < 2; ++m)
#pragma unroll
        for (int n = 0; n < 2; ++n) { acck[m][n] = zero; accg[m][n] = zero; }

    for (int k0 = 0; k0 < D; k0 += 32) {
        size_t kb = (size_t)k0 * 2;
        gload_lds16((const char*)fkb + gA + kb, smem + sdst);
        gload_lds16((const char*)fgb + gA + kb, smem + 4096 + sdst);
        gload_lds16((const char*)fkb + gB + kb, smem + 8192 + sdst);
        gload_lds16((const char*)fgb + gB + kb, smem + 12288 + sdst);
        __syncthreads();

        short8 ak[2], ag[2], bk[2], bg[2];
#pragma unroll
        for (int m = 0; m < 2; ++m) {
            ak[m] = *(const short8*)(smem + aoff[m]);
            ag[m] = *(const short8*)(smem + 4096 + aoff[m]);
        }
#pragma unroll
        for (int n = 0; n < 2; ++n) {
            bk[n] = *(const short8*)(smem + 8192 + boff[n]);
            bg[n] = *(const short8*)(smem + 12288 + boff[n]);
        }
        __builtin_amdgcn_s_setprio(1);
#pragma unroll
        for (int m = 0; m < 2; ++m)
#pragma unroll
            for (int n = 0; n < 2; ++n) {
                acck[m][n] = __builtin_amdgcn_mfma_f32_16x16x32_bf16(ak[m], bk[n], acck[m][n], 0, 0, 0);
                accg[m][n] = __builtin_amdgcn_mfma_f32_16x16x32_bf16(ag[m], bg[n], accg[m][n], 0, 0, 0);
            }
        __builtin_amdgcn_s_setprio(0);
        __syncthreads();
    }

    // --- epilogue: ratio + diag (in place) ---------------------------------
#pragma unroll
    for (int m = 0; m < 2; ++m)
#pragma unroll
        for (int j = 0; j < 4; ++j) {
            int lrow = wr * 32 + m * 16 + lg * 4 + j;
#pragma unroll
            for (int n = 0; n < 2; ++n) {
                float dk = acck[m][n][j];
                float dg = accg[m][n][j];
                float s = (dk + 1.0f + EPS_F) * __builtin_amdgcn_rcpf(dg + 1.0f + EPS_F);
                if (r0 + lrow == c0 + wc * 32 + n * 16 + lr) s = NEG_DIAG_F;
                acck[m][n][j] = s;
            }
        }

    // row maxes -> lmax[0..63]
#pragma unroll
    for (int m = 0; m < 2; ++m)
#pragma unroll
        for (int j = 0; j < 4; ++j) {
            float pm = fmaxf(acck[m][0][j], acck[m][1][j]);
#pragma unroll
            for (int off = 1; off < 16; off <<= 1)
                pm = fmaxf(pm, __shfl_xor(pm, off, 64));
            if (lr == 0) atomicMax(&lmax[wr * 32 + m * 16 + lg * 4 + j], __float_as_int(pm));
        }
    // col maxes -> lmax[64..127]
#pragma unroll
    for (int n = 0; n < 2; ++n) {
        float cm = acck[0][n][0];
#pragma unroll
        for (int m = 0; m < 2; ++m)
#pragma unroll
            for (int j = 0; j < 4; ++j) cm = fmaxf(cm, acck[m][n][j]);
        cm = fmaxf(cm, __shfl_xor(cm, 16, 64));
        cm = fmaxf(cm, __shfl_xor(cm, 32, 64));
        if (lg == 0) atomicMax(&lmax[64 + wc * 32 + n * 16 + lr], __float_as_int(cm));
    }

    // direct tile: bounce [row][col] then 256B-row coalesced stores
#pragma unroll
    for (int m = 0; m < 2; ++m)
#pragma unroll
        for (int n = 0; n < 2; ++n)
#pragma unroll
            for (int j = 0; j < 4; ++j)
                bnc[(wr * 32 + m * 16 + lg * 4 + j) * 68 + wc * 32 + n * 16 + lr] = acck[m][n][j];
    __syncthreads();   // bounce written + lmax atomics done

#pragma unroll
    for (int i = 0; i < 4; ++i) {
        int rr = i * 16 + (t >> 4);
        f32x4 v = *(const f32x4*)&bnc[rr * 68 + (t & 15) * 4];
        *(f32x4*)(out + (size_t)(r0 + rr) * N + c0 + (t & 15) * 4) = v;
    }
    if (t < 64) {
        P[(size_t)(r0 + t) * NPART + bx] = __int_as_float(lmax[t]);
    } else if (t < 128 && bx > by) {
        P[(size_t)(c0 + t - 64) * NPART + 64 + by] = __int_as_float(lmax[t]);
    }

    if (bx > by) {
        __syncthreads();   // direct-store reads done before overwrite
#pragma unroll
        for (int m = 0; m < 2; ++m)
#pragma unroll
            for (int n = 0; n < 2; ++n)
#pragma unroll
                for (int j = 0; j < 4; ++j)
                    bnc[(wc * 32 + n * 16 + lr) * 68 + wr * 32 + m * 16 + lg * 4 + j] = acck[m][n][j];
        __syncthreads();
#pragma unroll
        for (int i = 0; i < 4; ++i) {
            int rr = i * 16 + (t >> 4);
            f32x4 v = *(const f32x4*)&bnc[rr * 68 + (t & 15) * 4];
            *(f32x4*)(out + (size_t)(c0 + rr) * N + r0 + (t & 15) * 4) = v;
        }
    }
}

// ---------------------------------------------------------------------------
// Kernel 3: one block per row: m = max_j P[row][j]; out = exp(out - m).
// ---------------------------------------------------------------------------
__global__ void finalize_kernel(float* __restrict__ out, const float* __restrict__ P, int N) {
    int row = blockIdx.x;
    int t = threadIdx.x;            // 256
    int j = t & 63;
    float m = fmaxf(P[(size_t)row * NPART + j], P[(size_t)row * NPART + 64 + j]);
#pragma unroll
    for (int off = 1; off < 64; off <<= 1)
        m = fmaxf(m, __shfl_xor(m, off, 64));
    float4* o4 = (float4*)(out + (size_t)row * N);
    int n4 = N >> 2;
    for (int i = t; i < n4; i += 256) {
        float4 v = o4[i];
        v.x = __expf(v.x - m);
        v.y = __expf(v.y - m);
        v.z = __expf(v.z - m);
        v.w = __expf(v.w - m);
        o4[i] = v;
    }
}

// ---------------------------------------------------------------------------
extern "C" void kernel_launch(void* const* d_in, const int* in_sizes, int n_in,
                              void* d_out, int out_size, void* d_ws, size_t ws_size,
                              hipStream_t stream) {
    const float* fk = (const float*)d_in[1];
    const float* fg = (const float*)d_in[2];
    float* out = (float*)d_out;

    int N = (int)llround(sqrt((double)out_size));   // 4096
    int D = in_sizes[1] / N;                        // 256

    char* ws = (char*)d_ws;
    float* P = (float*)ws;                                          // N*128*4 = 2 MB
    __hip_bfloat16* fkb = (__hip_bfloat16*)(ws + (size_t)N * NPART * 4);
    __hip_bfloat16* fgb = (__hip_bfloat16*)(ws + (size_t)N * NPART * 4 + (size_t)N * D * 2);

    norm_cast_kernel<<<N, D, 0, stream>>>(fk, fg, fkb, fgb, P, N, D);

    gram64_kernel<<<dim3(N / 64, N / 64), 256, 0, stream>>>(fkb, fgb, out, P, N, D);

    finalize_kernel<<<N, 256, 0, stream>>>(out, P, N);
}